// Round 1
// baseline (959.617 us; speedup 1.0000x reference)
//
#include <hip/hip_runtime.h>
#include <hip/hip_bf16.h>
#include <cstdint>

typedef __attribute__((ext_vector_type(4))) float f4;
typedef __attribute__((ext_vector_type(4))) float f32x4;
typedef __attribute__((ext_vector_type(8))) __bf16 bf16x8;
typedef unsigned short ushort_t;
typedef unsigned int uint_t;

#define TTOK 2048
#define DDIM 2048
#define NEXP 64
#define TOPK 6
#define FDIM 1408
#define FSH  2816
#define NASSIGN (TTOK*TOPK)

// ---------- helpers ----------
__device__ __forceinline__ ushort_t f2bf(float f){
  uint_t u = __builtin_bit_cast(uint_t, f);
  u = (u + 0x7FFFu + ((u >> 16) & 1u)) >> 16;
  return (ushort_t)u;
}
__device__ __forceinline__ float bf2f(uint_t b){
  uint_t u = (b & 0xFFFFu) << 16;
  return __builtin_bit_cast(float, u);
}
__device__ __forceinline__ void gld_lds16(const void* g, void* l){
  __builtin_amdgcn_global_load_lds((const __attribute__((address_space(1))) uint_t*)g,
                                   (__attribute__((address_space(3))) uint_t*)l, 16, 0, 0);
}

// ---------- gate: logits + top-6 + renorm ----------
__global__ __launch_bounds__(256) void gate_topk_kernel(
    const float* __restrict__ x, const float* __restrict__ gw,
    int* __restrict__ topi, float* __restrict__ topw)
{
  __shared__ float xs[4*2048];
  __shared__ float lg[4*64];
  int tid = threadIdx.x;
  int t0 = blockIdx.x*4;
  const f4* xg = (const f4*)(x + (size_t)t0*DDIM);
  f4* xsv = (f4*)xs;
  for (int i = tid; i < 2048; i += 256) xsv[i] = xg[i];
  __syncthreads();
  int g = tid >> 6, l = tid & 63;
  int c = l & 3, er = l >> 2;
  const f4* xrow = (const f4*)(xs + g*2048 + c*512);
  #pragma unroll
  for (int eo = 0; eo < 4; ++eo){
    int e = eo*16 + er;
    const f4* wrow = (const f4*)(gw + (size_t)e*DDIM + c*512);
    float d = 0.f;
    #pragma unroll 4
    for (int j = 0; j < 128; ++j){
      f4 w = wrow[j], a = xrow[j];
      d += w.x*a.x + w.y*a.y + w.z*a.z + w.w*a.w;
    }
    d += __shfl_xor(d, 1);
    d += __shfl_xor(d, 2);
    if (c == 0) lg[g*64 + e] = d;
  }
  __syncthreads();
  float mv = lg[g*64 + l];
  float sv[6]; int si[6];
  #pragma unroll
  for (int s = 0; s < 6; ++s){
    float bv = mv; int bi = l;
    for (int off = 32; off > 0; off >>= 1){
      float ov = __shfl_xor(bv, off);
      int oi = __shfl_xor(bi, off);
      if (ov > bv || (ov == bv && oi < bi)){ bv = ov; bi = oi; }
    }
    sv[s] = bv; si[s] = bi;
    if (l == bi) mv = -3.4e38f;
  }
  if (l == 0){
    float sum = 0.f, wv[6];
    #pragma unroll
    for (int s = 0; s < 6; ++s){ wv[s] = __expf(sv[s] - sv[0]); sum += wv[s]; }
    float inv = 1.f/sum;
    int t = t0 + g;
    #pragma unroll
    for (int s = 0; s < 6; ++s){ topi[t*6+s] = si[s]; topw[t*6+s] = wv[s]*inv; }
  }
}

// ---------- x -> bf16 ----------
__global__ __launch_bounds__(256) void xcast_kernel(const float* __restrict__ x, ushort_t* __restrict__ xb){
  size_t base = ((size_t)blockIdx.x*256 + threadIdx.x)*8;
  f4 a = *(const f4*)(x + base);
  f4 b = *(const f4*)(x + base + 4);
  uint4 r;
  r.x = f2bf(a.x) | ((uint_t)f2bf(a.y)<<16);
  r.y = f2bf(a.z) | ((uint_t)f2bf(a.w)<<16);
  r.z = f2bf(b.x) | ((uint_t)f2bf(b.y)<<16);
  r.w = f2bf(b.z) | ((uint_t)f2bf(b.w)<<16);
  *(uint4*)(xb + base) = r;
}

// ---------- routing bookkeeping ----------
__global__ __launch_bounds__(256) void count_kernel(const int* __restrict__ topi, int* __restrict__ counts){
  int a = blockIdx.x*256 + threadIdx.x;
  if (a < NASSIGN) atomicAdd(&counts[topi[a]], 1);
}
__global__ void scan_kernel(const int* __restrict__ counts, int* __restrict__ offsets){
  if (threadIdx.x == 0){
    int s = 0;
    for (int e = 0; e < NEXP; ++e){ offsets[e] = s; s += counts[e]; }
    offsets[NEXP] = s;
  }
}
__global__ __launch_bounds__(256) void scatter_kernel(
    const int* __restrict__ topi, const float* __restrict__ topw,
    const int* __restrict__ offsets, int* __restrict__ cursor,
    int* __restrict__ row_token, float* __restrict__ row_w, int* __restrict__ row_assign)
{
  int a = blockIdx.x*256 + threadIdx.x;
  if (a < NASSIGN){
    int e = topi[a];
    int pos = atomicAdd(&cursor[e], 1);
    int r = offsets[e] + pos;
    row_token[r]  = a / 6;
    row_w[r]      = topw[a];
    row_assign[r] = a;
  }
}

// ---------- fused gate+up GEMM (+silu*mul) : out H bf16 ----------
// BM=256 BN=64 BK=64, 512 thr (8 waves, 4m x 2n), LDS 48KB, bf16 MFMA 16x16x32
__global__ __launch_bounds__(512, 2) void gemm_gateup_kernel(
    const ushort_t* __restrict__ A, const float* __restrict__ Bg0, const float* __restrict__ Bu0,
    ushort_t* __restrict__ H,
    const int* __restrict__ offsets, const int* __restrict__ row_token,
    const ushort_t* __restrict__ zerop,
    int N, int K, int lda, int n_mt, int n_nt, int Mfix)
{
  int nwg = gridDim.x;
  int chunk = nwg >> 3;
  int L = (blockIdx.x & 7)*chunk + (blockIdx.x >> 3);
  int e, mt, nt, row0, rowcnt;
  if (offsets){
    int per = n_mt*n_nt; e = L/per; int rem = L - e*per; mt = rem/n_nt; nt = rem - mt*n_nt;
    row0 = offsets[e]; rowcnt = offsets[e+1] - row0;
  } else { e = 0; nt = L/n_mt; mt = L - nt*n_mt; row0 = 0; rowcnt = Mfix; }
  int m0 = mt*256;
  if (m0 >= rowcnt) return;

  const float* Bg = Bg0 + (size_t)e*K*N + nt*64;
  const float* Bu = Bu0 + (size_t)e*K*N + nt*64;

  __shared__ ushort_t As[256*64];
  __shared__ ushort_t Bs[2][64*64];

  int tid = threadIdx.x;
  int lane = tid & 63;
  int wid = tid >> 6;
  int wm = wid & 3, wn = wid >> 2;

  // A row source pointers (gathered, swizzled source slot)
  const ushort_t* asrc[4];
  #pragma unroll
  for (int i = 0; i < 4; ++i){
    int r = (tid >> 3) + i*64;
    int gr = m0 + r;
    bool v = gr < rowcnt;
    int tok = row_token ? (v ? row_token[row0+gr] : 0) : gr;
    const ushort_t* p = v ? (A + (size_t)tok*lda) : zerop;
    int slot = (tid & 7) ^ (r & 7);
    asrc[i] = p + slot*8;
  }

  // B staging mapping: 256 thr per matrix, one 4x4 f32 block each
  int half = tid >> 8;
  int l256 = tid & 255;
  int bn4 = l256 & 15, bk4 = l256 >> 4;
  const float* Bsrc = half ? Bu : Bg;
  ushort_t* bdst[4];
  #pragma unroll
  for (int j = 0; j < 4; ++j){
    int n = bn4*4 + j;
    int slot = (bk4 >> 1) ^ (n & 7);
    bdst[j] = &Bs[half][n*64 + slot*8 + (bk4 & 1)*4];
  }

  f32x4 accG[4][2], accU[4][2];
  #pragma unroll
  for (int i=0;i<4;++i)
    #pragma unroll
    for (int j=0;j<2;++j){ accG[i][j] = f32x4{0.f,0.f,0.f,0.f}; accU[i][j] = f32x4{0.f,0.f,0.f,0.f}; }

  int nK = K >> 6;
  for (int ks = 0; ks < nK; ++ks){
    int k0 = ks << 6;
    #pragma unroll
    for (int i = 0; i < 4; ++i)
      gld_lds16(asrc[i] + k0, &As[i*4096 + tid*8]);
    const float* bp = Bsrc + (size_t)(k0 + bk4*4)*N + bn4*4;
    f4 v0 = *(const f4*)(bp);
    f4 v1 = *(const f4*)(bp + (size_t)N);
    f4 v2 = *(const f4*)(bp + 2*(size_t)N);
    f4 v3 = *(const f4*)(bp + 3*(size_t)N);
    #pragma unroll
    for (int j = 0; j < 4; ++j){
      uint2 pk;
      pk.x = f2bf(v0[j]) | ((uint_t)f2bf(v1[j]) << 16);
      pk.y = f2bf(v2[j]) | ((uint_t)f2bf(v3[j]) << 16);
      *(uint2*)bdst[j] = pk;
    }
    __syncthreads();
    #pragma unroll
    for (int kk = 0; kk < 2; ++kk){
      bf16x8 af[4], bg[2], bu[2];
      int kb = (kk << 2) + (lane >> 4);
      #pragma unroll
      for (int i = 0; i < 4; ++i){
        int ar = wm*64 + i*16 + (lane & 15);
        af[i] = *(const bf16x8*)&As[ar*64 + ((kb ^ (ar & 7)) << 3)];
      }
      #pragma unroll
      for (int j = 0; j < 2; ++j){
        int br = wn*32 + j*16 + (lane & 15);
        int idx = br*64 + ((kb ^ (br & 7)) << 3);
        bg[j] = *(const bf16x8*)&Bs[0][idx];
        bu[j] = *(const bf16x8*)&Bs[1][idx];
      }
      #pragma unroll
      for (int i = 0; i < 4; ++i)
        #pragma unroll
        for (int j = 0; j < 2; ++j){
          accG[i][j] = __builtin_amdgcn_mfma_f32_16x16x32_bf16(af[i], bg[j], accG[i][j], 0,0,0);
          accU[i][j] = __builtin_amdgcn_mfma_f32_16x16x32_bf16(af[i], bu[j], accU[i][j], 0,0,0);
        }
    }
    __syncthreads();
  }

  #pragma unroll
  for (int i = 0; i < 4; ++i)
    #pragma unroll
    for (int j = 0; j < 2; ++j){
      int col = nt*64 + wn*32 + j*16 + (lane & 15);
      #pragma unroll
      for (int q = 0; q < 4; ++q){
        int r = wm*64 + i*16 + ((lane >> 4) << 2) + q;
        int gr = m0 + r;
        if (gr < rowcnt){
          float gv = accG[i][j][q];
          float uv = accU[i][j][q];
          float hv = (gv / (1.f + __expf(-gv))) * uv;
          H[(size_t)(row0 + gr)*(size_t)N + col] = f2bf(hv);
        }
      }
    }
}

// ---------- down GEMM: routed -> bf16 per-assignment rows (weighted); shared -> f32 d_out ----------
__global__ __launch_bounds__(512, 2) void gemm_down_kernel(
    const ushort_t* __restrict__ A, const float* __restrict__ B0,
    ushort_t* __restrict__ outb, float* __restrict__ outf,
    const int* __restrict__ offsets, const float* __restrict__ row_w, const int* __restrict__ row_assign,
    const ushort_t* __restrict__ zerop,
    int N, int K, int lda, int n_mt, int n_nt, int Mfix)
{
  int nwg = gridDim.x;
  int chunk = nwg >> 3;
  int L = (blockIdx.x & 7)*chunk + (blockIdx.x >> 3);
  int e, mt, nt, row0, rowcnt;
  if (offsets){
    int per = n_mt*n_nt; e = L/per; int rem = L - e*per; mt = rem/n_nt; nt = rem - mt*n_nt;
    row0 = offsets[e]; rowcnt = offsets[e+1] - row0;
  } else { e = 0; nt = L/n_mt; mt = L - nt*n_mt; row0 = 0; rowcnt = Mfix; }
  int m0 = mt*256;
  if (m0 >= rowcnt) return;

  const float* B = B0 + (size_t)e*K*N + nt*64;

  __shared__ ushort_t As[256*64];
  __shared__ ushort_t Bs[64*64];
  __shared__ float Wr[256];
  __shared__ int Ar[256];

  int tid = threadIdx.x;
  int lane = tid & 63;
  int wid = tid >> 6;
  int wm = wid & 3, wn = wid >> 2;

  if (offsets){
    for (int t = tid; t < 256; t += 512){
      int gr = m0 + t;
      bool v = gr < rowcnt;
      Wr[t] = v ? row_w[row0+gr] : 0.f;
      Ar[t] = v ? row_assign[row0+gr] : 0;
    }
  }

  const ushort_t* asrc[4];
  #pragma unroll
  for (int i = 0; i < 4; ++i){
    int r = (tid >> 3) + i*64;
    int gr = m0 + r;
    bool v = gr < rowcnt;
    const ushort_t* p = v ? (A + (size_t)(row0+gr)*lda) : zerop;
    int slot = (tid & 7) ^ (r & 7);
    asrc[i] = p + slot*8;
  }

  int bn4 = tid & 15, bk8 = tid >> 4;   // 4x2 f32 block per thread
  ushort_t* bdst[4];
  #pragma unroll
  for (int j = 0; j < 4; ++j){
    int n = bn4*4 + j;
    int slot = (bk8 >> 2) ^ (n & 7);
    bdst[j] = &Bs[n*64 + slot*8 + (bk8 & 3)*2];
  }

  f32x4 acc[4][2];
  #pragma unroll
  for (int i=0;i<4;++i)
    #pragma unroll
    for (int j=0;j<2;++j) acc[i][j] = f32x4{0.f,0.f,0.f,0.f};

  int nK = K >> 6;
  for (int ks = 0; ks < nK; ++ks){
    int k0 = ks << 6;
    #pragma unroll
    for (int i = 0; i < 4; ++i)
      gld_lds16(asrc[i] + k0, &As[i*4096 + tid*8]);
    const float* bp = B + (size_t)(k0 + bk8*2)*N + bn4*4;
    f4 v0 = *(const f4*)(bp);
    f4 v1 = *(const f4*)(bp + (size_t)N);
    #pragma unroll
    for (int j = 0; j < 4; ++j){
      uint_t pk = f2bf(v0[j]) | ((uint_t)f2bf(v1[j]) << 16);
      *(uint_t*)bdst[j] = pk;
    }
    __syncthreads();
    #pragma unroll
    for (int kk = 0; kk < 2; ++kk){
      bf16x8 af[4], bb[2];
      int kb = (kk << 2) + (lane >> 4);
      #pragma unroll
      for (int i = 0; i < 4; ++i){
        int ar = wm*64 + i*16 + (lane & 15);
        af[i] = *(const bf16x8*)&As[ar*64 + ((kb ^ (ar & 7)) << 3)];
      }
      #pragma unroll
      for (int j = 0; j < 2; ++j){
        int br = wn*32 + j*16 + (lane & 15);
        bb[j] = *(const bf16x8*)&Bs[br*64 + ((kb ^ (br & 7)) << 3)];
      }
      #pragma unroll
      for (int i = 0; i < 4; ++i)
        #pragma unroll
        for (int j = 0; j < 2; ++j)
          acc[i][j] = __builtin_amdgcn_mfma_f32_16x16x32_bf16(af[i], bb[j], acc[i][j], 0,0,0);
    }
    __syncthreads();
  }

  #pragma unroll
  for (int i = 0; i < 4; ++i)
    #pragma unroll
    for (int j = 0; j < 2; ++j){
      int col = nt*64 + wn*32 + j*16 + (lane & 15);
      #pragma unroll
      for (int q = 0; q < 4; ++q){
        int r = wm*64 + i*16 + ((lane >> 4) << 2) + q;
        int gr = m0 + r;
        if (gr < rowcnt){
          float val = acc[i][j][q];
          if (offsets){
            outb[(size_t)Ar[r]*2048 + col] = f2bf(val * Wr[r]);
          } else {
            outf[(size_t)gr*2048 + col] = val;
          }
        }
      }
    }
}

// ---------- combine: out += sum_k out_assign[t*6+k] ----------
__global__ __launch_bounds__(256) void combine_kernel(const ushort_t* __restrict__ oa, float* __restrict__ out){
  size_t base = ((size_t)blockIdx.x*256 + threadIdx.x)*8;
  int t = (int)(base >> 11);
  int d = (int)(base & 2047);
  f4 s0 = *(const f4*)(out + base);
  f4 s1 = *(const f4*)(out + base + 4);
  #pragma unroll
  for (int k = 0; k < 6; ++k){
    const ushort_t* row = oa + (((size_t)(t*6+k)) << 11) + d;
    uint4 u = *(const uint4*)row;
    s0.x += bf2f(u.x); s0.y += bf2f(u.x >> 16);
    s0.z += bf2f(u.y); s0.w += bf2f(u.y >> 16);
    s1.x += bf2f(u.z); s1.y += bf2f(u.z >> 16);
    s1.z += bf2f(u.w); s1.w += bf2f(u.w >> 16);
  }
  *(f4*)(out + base) = s0;
  *(f4*)(out + base + 4) = s1;
}

extern "C" void kernel_launch(void* const* d_in, const int* in_sizes, int n_in,
                              void* d_out, int out_size, void* d_ws, size_t ws_size,
                              hipStream_t stream)
{
  const float* x       = (const float*)d_in[0];
  const float* gate_w  = (const float*)d_in[1];
  const float* w_gate  = (const float*)d_in[2];
  const float* w_up    = (const float*)d_in[3];
  const float* w_down  = (const float*)d_in[4];
  const float* ws_gate = (const float*)d_in[5];
  const float* ws_up   = (const float*)d_in[6];
  const float* ws_down = (const float*)d_in[7];
  float* out = (float*)d_out;

  char* ws = (char*)d_ws;
  int*      topi       = (int*)(ws + 0);           // 49152
  float*    topw       = (float*)(ws + 49152);     // 49152
  int*      counts     = (int*)(ws + 98304);       // 256
  int*      cursor     = (int*)(ws + 98560);       // 256
  int*      offsets    = (int*)(ws + 98816);       // 512
  int*      row_token  = (int*)(ws + 99328);       // 49152
  float*    row_w      = (float*)(ws + 148480);    // 49152
  int*      row_assign = (int*)(ws + 197632);      // 49152
  ushort_t* zerop      = (ushort_t*)(ws + 262144); // 8192 zeros
  ushort_t* xb         = (ushort_t*)(ws + 524288);   // 8.39 MB
  ushort_t* Hbuf       = (ushort_t*)(ws + 8912896);  // 34.6 MB  [12288 x 1408] bf16
  ushort_t* Shbuf      = (ushort_t*)(ws + 43515904); // 11.5 MB  [2048 x 2816] bf16
  ushort_t* oa         = (ushort_t*)(ws + 55050240); // 50.3 MB  [12288 x 2048] bf16
  (void)ws_size; (void)in_sizes; (void)n_in; (void)out_size;

  hipMemsetAsync(ws + 98304, 0, 512, stream);     // counts + cursor
  hipMemsetAsync(zerop, 0, 8192, stream);

  gate_topk_kernel<<<512, 256, 0, stream>>>(x, gate_w, topi, topw);
  xcast_kernel<<<2048, 256, 0, stream>>>(x, xb);
  count_kernel<<<48, 256, 0, stream>>>(topi, counts);
  scan_kernel<<<1, 64, 0, stream>>>(counts, offsets);
  scatter_kernel<<<48, 256, 0, stream>>>(topi, topw, offsets, cursor, row_token, row_w, row_assign);

  // routed gate+up: 64 experts x 2 mtiles x 22 ntiles
  gemm_gateup_kernel<<<2816, 512, 0, stream>>>(xb, w_gate, w_up, Hbuf, offsets, row_token, zerop,
                                               FDIM, DDIM, DDIM, 2, 22, 0);
  // shared gate+up: 44 ntiles x 8 mtiles
  gemm_gateup_kernel<<<352, 512, 0, stream>>>(xb, ws_gate, ws_up, Shbuf, nullptr, nullptr, zerop,
                                              FSH, DDIM, DDIM, 8, 44, TTOK);
  // shared down -> writes d_out directly (f32)
  gemm_down_kernel<<<256, 512, 0, stream>>>(Shbuf, ws_down, nullptr, out, nullptr, nullptr, nullptr, zerop,
                                            DDIM, FSH, FSH, 8, 32, TTOK);
  // routed down -> weighted bf16 per-assignment rows
  gemm_down_kernel<<<4096, 512, 0, stream>>>(Hbuf, w_down, oa, nullptr, offsets, row_w, row_assign, zerop,
                                             DDIM, FDIM, FDIM, 2, 32, 0);
  // combine: out += sum of 6 assignment rows
  combine_kernel<<<2048, 256, 0, stream>>>(oa, out);
}